// Round 1
// baseline (2038.325 us; speedup 1.0000x reference)
//
#include <hip/hip_runtime.h>
#include <math.h>

// One thread per batch element. Activations in LDS as h[k][lane] (lane-private
// column -> no sync needed, stride-64-floats => 2 lanes/bank = conflict-free).
// Weights read with wave-uniform indices -> scalar (s_load) path, SGPR operand
// feeds v_fma directly.

__device__ __forceinline__ float gelu_exact(float x) {
    return 0.5f * x * (1.0f + erff(x * 0.70710678118654752f));
}

__global__ void __launch_bounds__(64) stress_kernel(
    const float* __restrict__ F,
    const float* __restrict__ Cin,
    const float* __restrict__ w1, const float* __restrict__ b1,
    const float* __restrict__ w2, const float* __restrict__ b2,
    const float* __restrict__ w3, const float* __restrict__ b3,
    const float* __restrict__ w4, const float* __restrict__ b4,
    const float* __restrict__ w5, const float* __restrict__ b5,
    const float* __restrict__ trajw, const int* __restrict__ traj_ids,
    float* __restrict__ out, int Btotal)
{
    __shared__ float hbuf[64 * 64];   // [k][lane], 16 KiB
    const int lane = threadIdx.x;
    const int b = blockIdx.x * 64 + lane;
    if (b >= Btotal) return;          // no barriers in kernel -> early return safe

    // ---- load F (9), stash C and latent straight into feature rows ----
    float f[9];
    const float* Fp = F + b * 9;
    #pragma unroll
    for (int i = 0; i < 9; ++i) f[i] = Fp[i];

    const float* Cp = Cin + b * 9;
    #pragma unroll
    for (int i = 0; i < 9; ++i) hbuf[(16 + i) * 64 + lane] = Cp[i];

    const int tid0 = traj_ids[0];
    const float* lp = trajw + tid0 * 32;
    #pragma unroll
    for (int e = 0; e < 32; ++e) hbuf[(25 + e) * 64 + lane] = lp[e];   // uniform scalar loads

    // ---- FtF (symmetric) ----
    float s00 = fmaf(f[0], f[0], fmaf(f[3], f[3], f[6] * f[6]));
    float s01 = fmaf(f[0], f[1], fmaf(f[3], f[4], f[6] * f[7]));
    float s02 = fmaf(f[0], f[2], fmaf(f[3], f[5], f[6] * f[8]));
    float s11 = fmaf(f[1], f[1], fmaf(f[4], f[4], f[7] * f[7]));
    float s12 = fmaf(f[1], f[2], fmaf(f[4], f[5], f[7] * f[8]));
    float s22 = fmaf(f[2], f[2], fmaf(f[5], f[5], f[8] * f[8]));

    // I2 = FtF row-major, feature rows 3..11
    hbuf[ 3 * 64 + lane] = s00;  hbuf[ 4 * 64 + lane] = s01;  hbuf[ 5 * 64 + lane] = s02;
    hbuf[ 6 * 64 + lane] = s01;  hbuf[ 7 * 64 + lane] = s11;  hbuf[ 8 * 64 + lane] = s12;
    hbuf[ 9 * 64 + lane] = s02;  hbuf[10 * 64 + lane] = s12;  hbuf[11 * 64 + lane] = s22;

    // ---- det / F00 features ----
    float det = f[0] * (f[4] * f[8] - f[5] * f[7])
              - f[1] * (f[3] * f[8] - f[5] * f[6])
              + f[2] * (f[3] * f[7] - f[4] * f[6]);
    float detc = det < 0.0f ? 1e-9f : det;
    hbuf[12 * 64 + lane] = detc;
    hbuf[13 * 64 + lane] = logf(detc);
    float f00c = fmaxf(f[0], 1e-6f);
    hbuf[14 * 64 + lane] = f00c;
    hbuf[15 * 64 + lane] = logf(f00c);

    // ---- Jacobi eigendecomposition of S = FtF (4 sweeps) ----
    float a00 = s00, a01 = s01, a02 = s02, a11 = s11, a12 = s12, a22 = s22;
    float v00 = 1.f, v01 = 0.f, v02 = 0.f;
    float v10 = 0.f, v11 = 1.f, v12 = 0.f;
    float v20 = 0.f, v21 = 0.f, v22 = 1.f;

    auto rot = [](float& app, float& aqq, float& apq, float& arp, float& arq,
                  float& Vp0, float& Vq0, float& Vp1, float& Vq1, float& Vp2, float& Vq2) {
        float pq = apq;
        if (fabsf(pq) > 1e-20f) {
            float tau = (aqq - app) / (2.0f * pq);
            float t = copysignf(1.0f / (fabsf(tau) + sqrtf(fmaf(tau, tau, 1.0f))), tau);
            float c = 1.0f / sqrtf(fmaf(t, t, 1.0f));
            float s = t * c;
            app = app - t * pq;
            aqq = aqq + t * pq;
            apq = 0.0f;
            float rp = arp, rq = arq;
            arp = c * rp - s * rq;
            arq = s * rp + c * rq;
            float x0 = Vp0, y0 = Vq0; Vp0 = c * x0 - s * y0; Vq0 = s * x0 + c * y0;
            float x1 = Vp1, y1 = Vq1; Vp1 = c * x1 - s * y1; Vq1 = s * x1 + c * y1;
            float x2 = Vp2, y2 = Vq2; Vp2 = c * x2 - s * y2; Vq2 = s * x2 + c * y2;
        }
    };

    #pragma unroll
    for (int sweep = 0; sweep < 4; ++sweep) {
        rot(a00, a11, a01, a02, a12, v00, v01, v10, v11, v20, v21);  // (p,q)=(0,1), r=2
        rot(a00, a22, a02, a01, a12, v00, v02, v10, v12, v20, v22);  // (0,2), r=1
        rot(a11, a22, a12, a01, a02, v01, v02, v11, v12, v21, v22);  // (1,2), r=0
    }

    // ---- sort eigenvalues descending (swap V columns accordingly) ----
    #define CSWAP(La, Lb, pA0, pB0, pA1, pB1, pA2, pB2)                         \
        if (La < Lb) {                                                          \
            float t_;                                                           \
            t_ = La; La = Lb; Lb = t_;                                          \
            t_ = pA0; pA0 = pB0; pB0 = t_;                                      \
            t_ = pA1; pA1 = pB1; pB1 = t_;                                      \
            t_ = pA2; pA2 = pB2; pB2 = t_;                                      \
        }
    CSWAP(a00, a11, v00, v01, v10, v11, v20, v21)
    CSWAP(a00, a22, v00, v02, v10, v12, v20, v22)
    CSWAP(a11, a22, v01, v02, v11, v12, v21, v22)
    #undef CSWAP

    float sg0 = sqrtf(fmaxf(a00, 0.0f));
    float sg1 = sqrtf(fmaxf(a11, 0.0f));
    float sg2 = sqrtf(fmaxf(a22, 0.0f));
    hbuf[0 * 64 + lane] = sg0;
    hbuf[1 * 64 + lane] = sg1;
    hbuf[2 * 64 + lane] = sg2;

    // ---- R = F * V * diag(1/sigma) * V^T  (= U @ Vh of the SVD) ----
    float i0 = 1.0f / fmaxf(sg0, 1e-12f);
    float i1 = 1.0f / fmaxf(sg1, 1e-12f);
    float i2 = 1.0f / fmaxf(sg2, 1e-12f);
    float A00 = i0 * v00 * v00 + i1 * v01 * v01 + i2 * v02 * v02;
    float A01 = i0 * v00 * v10 + i1 * v01 * v11 + i2 * v02 * v12;
    float A02 = i0 * v00 * v20 + i1 * v01 * v21 + i2 * v02 * v22;
    float A11 = i0 * v10 * v10 + i1 * v11 * v11 + i2 * v12 * v12;
    float A12 = i0 * v10 * v20 + i1 * v11 * v21 + i2 * v12 * v22;
    float A22 = i0 * v20 * v20 + i1 * v21 * v21 + i2 * v22 * v22;

    float R00 = f[0] * A00 + f[1] * A01 + f[2] * A02;
    float R01 = f[0] * A01 + f[1] * A11 + f[2] * A12;
    float R02 = f[0] * A02 + f[1] * A12 + f[2] * A22;
    float R10 = f[3] * A00 + f[4] * A01 + f[5] * A02;
    float R11 = f[3] * A01 + f[4] * A11 + f[5] * A12;
    float R12 = f[3] * A02 + f[4] * A12 + f[5] * A22;
    float R20 = f[6] * A00 + f[7] * A01 + f[8] * A02;
    float R21 = f[6] * A01 + f[7] * A11 + f[8] * A12;
    float R22 = f[6] * A02 + f[7] * A12 + f[8] * A22;

    // ---- MLP: hidden layers with exact GELU; h lives in hbuf[k*64+lane] ----
    auto mlp_layer = [&](const float* __restrict__ W, const float* __restrict__ bias, int K) {
        float acc[64];
        #pragma unroll
        for (int j = 0; j < 64; ++j) acc[j] = bias[j];     // uniform scalar loads
        for (int k = 0; k < K; ++k) {
            float hk = hbuf[k * 64 + lane];
            const float* wr = W + k * 64;                   // uniform row -> s_load_dwordx16
            #pragma unroll
            for (int j = 0; j < 64; ++j) acc[j] = fmaf(hk, wr[j], acc[j]);
        }
        #pragma unroll
        for (int j = 0; j < 64; ++j) hbuf[j * 64 + lane] = gelu_exact(acc[j]);
    };

    mlp_layer(w1, b1, 57);
    mlp_layer(w2, b2, 64);
    mlp_layer(w3, b3, 64);
    mlp_layer(w4, b4, 64);

    // ---- output layer 64 -> 9 (no activation) ----
    float o[9];
    #pragma unroll
    for (int j = 0; j < 9; ++j) o[j] = b5[j];
    for (int k = 0; k < 64; ++k) {
        float hk = hbuf[k * 64 + lane];
        const float* wr = w5 + k * 9;
        #pragma unroll
        for (int j = 0; j < 9; ++j) o[j] = fmaf(hk, wr[j], o[j]);
    }

    // ---- symmetrize, P = R*xs, cauchy = P*F^T ----
    float xs00 = o[0];
    float xs01 = 0.5f * (o[1] + o[3]);
    float xs02 = 0.5f * (o[2] + o[6]);
    float xs11 = o[4];
    float xs12 = 0.5f * (o[5] + o[7]);
    float xs22 = o[8];

    float P00 = R00 * xs00 + R01 * xs01 + R02 * xs02;
    float P01 = R00 * xs01 + R01 * xs11 + R02 * xs12;
    float P02 = R00 * xs02 + R01 * xs12 + R02 * xs22;
    float P10 = R10 * xs00 + R11 * xs01 + R12 * xs02;
    float P11 = R10 * xs01 + R11 * xs11 + R12 * xs12;
    float P12 = R10 * xs02 + R11 * xs12 + R12 * xs22;
    float P20 = R20 * xs00 + R21 * xs01 + R22 * xs02;
    float P21 = R20 * xs01 + R21 * xs11 + R22 * xs12;
    float P22 = R20 * xs02 + R21 * xs12 + R22 * xs22;

    float* op = out + b * 9;
    // cauchy[i][j] = sum_k P[i][k] * F[j][k]
    op[0] = P00 * f[0] + P01 * f[1] + P02 * f[2];
    op[1] = P00 * f[3] + P01 * f[4] + P02 * f[5];
    op[2] = P00 * f[6] + P01 * f[7] + P02 * f[8];
    op[3] = P10 * f[0] + P11 * f[1] + P12 * f[2];
    op[4] = P10 * f[3] + P11 * f[4] + P12 * f[5];
    op[5] = P10 * f[6] + P11 * f[7] + P12 * f[8];
    op[6] = P20 * f[0] + P21 * f[1] + P22 * f[2];
    op[7] = P20 * f[3] + P21 * f[4] + P22 * f[5];
    op[8] = P20 * f[6] + P21 * f[7] + P22 * f[8];
}

extern "C" void kernel_launch(void* const* d_in, const int* in_sizes, int n_in,
                              void* d_out, int out_size, void* d_ws, size_t ws_size,
                              hipStream_t stream) {
    const float* F     = (const float*)d_in[0];
    const float* C     = (const float*)d_in[1];
    const float* w1    = (const float*)d_in[2];
    const float* b1    = (const float*)d_in[3];
    const float* w2    = (const float*)d_in[4];
    const float* b2    = (const float*)d_in[5];
    const float* w3    = (const float*)d_in[6];
    const float* b3    = (const float*)d_in[7];
    const float* w4    = (const float*)d_in[8];
    const float* b4    = (const float*)d_in[9];
    const float* w5    = (const float*)d_in[10];
    const float* b5    = (const float*)d_in[11];
    const float* trajw = (const float*)d_in[12];
    const int*   tids  = (const int*)d_in[13];
    float* out = (float*)d_out;

    int B = in_sizes[0] / 9;
    int grid = (B + 63) / 64;
    stress_kernel<<<grid, 64, 0, stream>>>(F, C, w1, b1, w2, b2, w3, b3, w4, b4,
                                           w5, b5, trajw, tids, out, B);
}

// Round 2
// 469.835 us; speedup vs baseline: 4.3384x; 4.3384x over previous
//
#include <hip/hip_runtime.h>
#include <math.h>

typedef short short8 __attribute__((ext_vector_type(8)));
typedef float f32x4  __attribute__((ext_vector_type(4)));
typedef unsigned short ushort_t;

// ---------- bf16 helpers (manual, exact RNE) ----------
__device__ __forceinline__ unsigned short f2bf(float x) {
    union { float f; unsigned u; } v; v.f = x;
    unsigned r = v.u + 0x7fffu + ((v.u >> 16) & 1u);
    return (unsigned short)(r >> 16);
}
__device__ __forceinline__ float bf2f(unsigned short u) {
    union { unsigned u; float f; } v; v.u = ((unsigned)u) << 16;
    return v.f;
}

__device__ __forceinline__ f32x4 mfma_bf16(short8 a, short8 b, f32x4 c) {
    return __builtin_amdgcn_mfma_f32_16x16x32_bf16(a, b, c, 0, 0, 0);
}

// gelu exact-form: 0.5*x*(1+erf(x/sqrt(2))), erf via A&S 7.1.26 (|eps|<=1.5e-7)
__device__ __forceinline__ float gelu(float x) {
    float z  = x * 0.70710678118654752f;
    float az = fabsf(z);
    float t  = 1.0f / fmaf(0.3275911f, az, 1.0f);
    float poly = fmaf(fmaf(fmaf(fmaf(1.061405429f, t, -1.453152027f), t,
                       1.421413741f), t, -0.284496736f), t, 0.254829592f);
    float e  = __expf(-az * az);
    float erfa = 1.0f - poly * t * e;                    // erf(|z|)
    float erfz = copysignf(erfa, z);
    return 0.5f * x * (1.0f + erfz);
}

// ---------- prep kernel: fp32 weights -> frag-ordered bf16 hi/lo in d_ws ----
// layout (u16 units): layer l base = l*8192; blob bi=((c*4+nt)*2+p) at bi*512;
// element (lane, j) at lane*8+j. value = W[c*32+(lane>>4)*8+j][nt*16+(lane&15)]
__global__ void prep_weights(const float* __restrict__ w1, const float* __restrict__ w2,
                             const float* __restrict__ w3, const float* __restrict__ w4,
                             unsigned short* __restrict__ wsu)
{
    int tid = blockIdx.x * blockDim.x + threadIdx.x;   // 4096 rows
    if (tid >= 4096) return;
    int l    = tid >> 10;
    int rem  = tid & 1023;
    int bi   = rem >> 6;
    int lane = rem & 63;
    int c  = bi >> 3;
    int nt = (bi >> 1) & 3;
    int p  = bi & 1;
    const float* W = (l == 0) ? w1 : (l == 1) ? w2 : (l == 2) ? w3 : w4;
    int K = (l == 0) ? 57 : 64;
    unsigned short* dst = wsu + l * 8192 + bi * 512 + lane * 8;
    int kb = c * 32 + (lane >> 4) * 8;
    int n  = nt * 16 + (lane & 15);
    #pragma unroll
    for (int j = 0; j < 8; ++j) {
        int k = kb + j;
        float v = (k < K) ? W[k * 64 + n] : 0.0f;
        unsigned short hi = f2bf(v);
        unsigned short o;
        if (p == 0) o = hi;
        else        o = f2bf(v - bf2f(hi));
        dst[j] = o;
    }
}

// ---------- main kernel ----------
#define STRIDE 72            // u16 per activation row (144 B, 16B aligned)
#define PLANE  (128 * 72)    // u16 per plane

__global__ void __launch_bounds__(128) stress_main(
    const float* __restrict__ F, const float* __restrict__ Cin,
    const float* __restrict__ b1, const float* __restrict__ b2,
    const float* __restrict__ b3, const float* __restrict__ b4,
    const float* __restrict__ w5, const float* __restrict__ b5,
    const float* __restrict__ trajw, const int* __restrict__ traj_ids,
    const unsigned short* __restrict__ wfrag,
    float* __restrict__ out, int Btotal)
{
    __shared__ unsigned short hl[2 * PLANE];   // 36,864 B
    const int t = threadIdx.x;                 // 0..127, == block-local row m
    const int b = blockIdx.x * 128 + t;
    const bool live = (b < Btotal);

    // ================= prologue: features + polar decomposition ============
    float f[9];
    float R00=0,R01=0,R02=0,R10=0,R11=0,R12=0,R20=0,R21=0,R22=0;
    float fv[64];
    #pragma unroll
    for (int i = 57; i < 64; ++i) fv[i] = 0.0f;

    if (live) {
        const float* Fp = F + b * 9;
        #pragma unroll
        for (int i = 0; i < 9; ++i) f[i] = Fp[i];
        const float* Cp = Cin + b * 9;
        #pragma unroll
        for (int i = 0; i < 9; ++i) fv[16 + i] = Cp[i];
        const int tid0 = traj_ids[0];
        const float* lp = trajw + tid0 * 32;
        #pragma unroll
        for (int e = 0; e < 32; ++e) fv[25 + e] = lp[e];

        float s00 = fmaf(f[0], f[0], fmaf(f[3], f[3], f[6] * f[6]));
        float s01 = fmaf(f[0], f[1], fmaf(f[3], f[4], f[6] * f[7]));
        float s02 = fmaf(f[0], f[2], fmaf(f[3], f[5], f[6] * f[8]));
        float s11 = fmaf(f[1], f[1], fmaf(f[4], f[4], f[7] * f[7]));
        float s12 = fmaf(f[1], f[2], fmaf(f[4], f[5], f[7] * f[8]));
        float s22 = fmaf(f[2], f[2], fmaf(f[5], f[5], f[8] * f[8]));
        fv[3] = s00; fv[4] = s01; fv[5] = s02;
        fv[6] = s01; fv[7] = s11; fv[8] = s12;
        fv[9] = s02; fv[10] = s12; fv[11] = s22;

        float det = f[0] * (f[4] * f[8] - f[5] * f[7])
                  - f[1] * (f[3] * f[8] - f[5] * f[6])
                  + f[2] * (f[3] * f[7] - f[4] * f[6]);
        float detc = det < 0.0f ? 1e-9f : det;
        fv[12] = detc;  fv[13] = logf(detc);
        float f00c = fmaxf(f[0], 1e-6f);
        fv[14] = f00c;  fv[15] = logf(f00c);

        // Jacobi eigendecomposition of FtF (verified in round 1)
        float a00 = s00, a01 = s01, a02 = s02, a11 = s11, a12 = s12, a22 = s22;
        float v00 = 1.f, v01 = 0.f, v02 = 0.f;
        float v10 = 0.f, v11 = 1.f, v12 = 0.f;
        float v20 = 0.f, v21 = 0.f, v22 = 1.f;
        auto rot = [](float& app, float& aqq, float& apq, float& arp, float& arq,
                      float& Vp0, float& Vq0, float& Vp1, float& Vq1, float& Vp2, float& Vq2) {
            float pq = apq;
            if (fabsf(pq) > 1e-20f) {
                float tau = (aqq - app) / (2.0f * pq);
                float tt = copysignf(1.0f / (fabsf(tau) + sqrtf(fmaf(tau, tau, 1.0f))), tau);
                float cc = 1.0f / sqrtf(fmaf(tt, tt, 1.0f));
                float ss = tt * cc;
                app = app - tt * pq;  aqq = aqq + tt * pq;  apq = 0.0f;
                float rp = arp, rq = arq;
                arp = cc * rp - ss * rq;  arq = ss * rp + cc * rq;
                float x0 = Vp0, y0 = Vq0; Vp0 = cc * x0 - ss * y0; Vq0 = ss * x0 + cc * y0;
                float x1 = Vp1, y1 = Vq1; Vp1 = cc * x1 - ss * y1; Vq1 = ss * x1 + cc * y1;
                float x2 = Vp2, y2 = Vq2; Vp2 = cc * x2 - ss * y2; Vq2 = ss * x2 + cc * y2;
            }
        };
        #pragma unroll
        for (int sweep = 0; sweep < 4; ++sweep) {
            rot(a00, a11, a01, a02, a12, v00, v01, v10, v11, v20, v21);
            rot(a00, a22, a02, a01, a12, v00, v02, v10, v12, v20, v22);
            rot(a11, a22, a12, a01, a02, v01, v02, v11, v12, v21, v22);
        }
        #define CSWAP(La, Lb, pA0, pB0, pA1, pB1, pA2, pB2)                     \
            if (La < Lb) { float t_;                                            \
                t_ = La; La = Lb; Lb = t_;   t_ = pA0; pA0 = pB0; pB0 = t_;     \
                t_ = pA1; pA1 = pB1; pB1 = t_; t_ = pA2; pA2 = pB2; pB2 = t_; }
        CSWAP(a00, a11, v00, v01, v10, v11, v20, v21)
        CSWAP(a00, a22, v00, v02, v10, v12, v20, v22)
        CSWAP(a11, a22, v01, v02, v11, v12, v21, v22)
        #undef CSWAP

        float sg0 = sqrtf(fmaxf(a00, 0.0f));
        float sg1 = sqrtf(fmaxf(a11, 0.0f));
        float sg2 = sqrtf(fmaxf(a22, 0.0f));
        fv[0] = sg0; fv[1] = sg1; fv[2] = sg2;

        float i0 = 1.0f / fmaxf(sg0, 1e-12f);
        float i1 = 1.0f / fmaxf(sg1, 1e-12f);
        float i2 = 1.0f / fmaxf(sg2, 1e-12f);
        float A00 = i0*v00*v00 + i1*v01*v01 + i2*v02*v02;
        float A01 = i0*v00*v10 + i1*v01*v11 + i2*v02*v12;
        float A02 = i0*v00*v20 + i1*v01*v21 + i2*v02*v22;
        float A11 = i0*v10*v10 + i1*v11*v11 + i2*v12*v12;
        float A12 = i0*v10*v20 + i1*v11*v21 + i2*v12*v22;
        float A22 = i0*v20*v20 + i1*v21*v21 + i2*v22*v22;
        R00 = f[0]*A00 + f[1]*A01 + f[2]*A02;
        R01 = f[0]*A01 + f[1]*A11 + f[2]*A12;
        R02 = f[0]*A02 + f[1]*A12 + f[2]*A22;
        R10 = f[3]*A00 + f[4]*A01 + f[5]*A02;
        R11 = f[3]*A01 + f[4]*A11 + f[5]*A12;
        R12 = f[3]*A02 + f[4]*A12 + f[5]*A22;
        R20 = f[6]*A00 + f[7]*A01 + f[8]*A02;
        R21 = f[6]*A01 + f[7]*A11 + f[8]*A12;
        R22 = f[6]*A02 + f[7]*A12 + f[8]*A22;
    } else {
        #pragma unroll
        for (int i = 0; i < 57; ++i) fv[i] = 0.0f;
        #pragma unroll
        for (int i = 0; i < 9; ++i) f[i] = 0.0f;
    }

    // write feature row (hi/lo planes), 8x ds_write_b128 each
    {
        unsigned short* rowh = hl + t * STRIDE;
        unsigned short* rowl = hl + PLANE + t * STRIDE;
        #pragma unroll
        for (int ch = 0; ch < 8; ++ch) {
            short8 vh, vl;
            #pragma unroll
            for (int j = 0; j < 8; ++j) {
                float x = fv[ch * 8 + j];
                unsigned short hb = f2bf(x);
                unsigned short lb = f2bf(x - bf2f(hb));
                vh[j] = (short)hb; vl[j] = (short)lb;
            }
            *(short8*)(rowh + ch * 8) = vh;
            *(short8*)(rowl + ch * 8) = vl;
        }
    }

    // ================= MLP: 4 x (64->64, gelu) via split-bf16 MFMA ==========
    // Wave-private rows: wave wv owns m in [wv*64, wv*64+64) == its own lanes'
    // elements -> no __syncthreads anywhere.
    const int wv   = t >> 6;
    const int lane = t & 63;
    const int q    = lane >> 4;
    const int r16  = lane & 15;
    const int mbase = wv * 64;

    const float* biases[4] = { b1, b2, b3, b4 };
    for (int l = 0; l < 4; ++l) {
        short8 Bh[2][4], Bl[2][4];
        const unsigned short* wb = wfrag + l * 8192;
        #pragma unroll
        for (int c = 0; c < 2; ++c)
            #pragma unroll
            for (int nt = 0; nt < 4; ++nt) {
                Bh[c][nt] = *(const short8*)(wb + ((c * 4 + nt) * 2 + 0) * 512 + lane * 8);
                Bl[c][nt] = *(const short8*)(wb + ((c * 4 + nt) * 2 + 1) * 512 + lane * 8);
            }
        float bv[4];
        #pragma unroll
        for (int nt = 0; nt < 4; ++nt) bv[nt] = biases[l][nt * 16 + r16];

        #pragma unroll
        for (int mt = 0; mt < 4; ++mt) {
            const unsigned short* ra = hl + (mbase + mt * 16 + r16) * STRIDE + q * 8;
            short8 Ah0 = *(const short8*)(ra);
            short8 Ah1 = *(const short8*)(ra + 32);
            short8 Al0 = *(const short8*)(ra + PLANE);
            short8 Al1 = *(const short8*)(ra + PLANE + 32);
            #pragma unroll
            for (int nt = 0; nt < 4; ++nt) {
                f32x4 acc = { bv[nt], bv[nt], bv[nt], bv[nt] };
                acc = mfma_bf16(Ah0, Bh[0][nt], acc);
                acc = mfma_bf16(Ah1, Bh[1][nt], acc);
                acc = mfma_bf16(Al0, Bh[0][nt], acc);
                acc = mfma_bf16(Al1, Bh[1][nt], acc);
                acc = mfma_bf16(Ah0, Bl[0][nt], acc);
                acc = mfma_bf16(Ah1, Bl[1][nt], acc);
                #pragma unroll
                for (int r = 0; r < 4; ++r) {
                    float g = gelu(acc[r]);
                    unsigned short hb = f2bf(g);
                    unsigned short lb = f2bf(g - bf2f(hb));
                    int mrow = mbase + mt * 16 + q * 4 + r;
                    hl[mrow * STRIDE + nt * 16 + r16] = hb;
                    hl[PLANE + mrow * STRIDE + nt * 16 + r16] = lb;
                }
            }
        }
    }

    // ================= epilogue: 64->9 fp32, symmetrize, R*xs*F^T ===========
    if (!live) return;

    float h[64];
    {
        const unsigned short* rh = hl + t * STRIDE;
        const unsigned short* rl = hl + PLANE + t * STRIDE;
        #pragma unroll
        for (int ch = 0; ch < 8; ++ch) {
            short8 vh = *(const short8*)(rh + ch * 8);
            short8 vl = *(const short8*)(rl + ch * 8);
            #pragma unroll
            for (int j = 0; j < 8; ++j)
                h[ch * 8 + j] = bf2f((unsigned short)vh[j]) + bf2f((unsigned short)vl[j]);
        }
    }

    float o[9];
    #pragma unroll
    for (int j = 0; j < 9; ++j) o[j] = b5[j];
    for (int k = 0; k < 64; ++k) {
        const float* wr = w5 + k * 9;       // wave-uniform -> s_load, 2.3 KB resident
        float hk = h[k];
        #pragma unroll
        for (int j = 0; j < 9; ++j) o[j] = fmaf(hk, wr[j], o[j]);
    }

    float xs00 = o[0];
    float xs01 = 0.5f * (o[1] + o[3]);
    float xs02 = 0.5f * (o[2] + o[6]);
    float xs11 = o[4];
    float xs12 = 0.5f * (o[5] + o[7]);
    float xs22 = o[8];

    float P00 = R00*xs00 + R01*xs01 + R02*xs02;
    float P01 = R00*xs01 + R01*xs11 + R02*xs12;
    float P02 = R00*xs02 + R01*xs12 + R02*xs22;
    float P10 = R10*xs00 + R11*xs01 + R12*xs02;
    float P11 = R10*xs01 + R11*xs11 + R12*xs12;
    float P12 = R10*xs02 + R11*xs12 + R12*xs22;
    float P20 = R20*xs00 + R21*xs01 + R22*xs02;
    float P21 = R20*xs01 + R21*xs11 + R22*xs12;
    float P22 = R20*xs02 + R21*xs12 + R22*xs22;

    float* op = out + b * 9;
    op[0] = P00*f[0] + P01*f[1] + P02*f[2];
    op[1] = P00*f[3] + P01*f[4] + P02*f[5];
    op[2] = P00*f[6] + P01*f[7] + P02*f[8];
    op[3] = P10*f[0] + P11*f[1] + P12*f[2];
    op[4] = P10*f[3] + P11*f[4] + P12*f[5];
    op[5] = P10*f[6] + P11*f[7] + P12*f[8];
    op[6] = P20*f[0] + P21*f[1] + P22*f[2];
    op[7] = P20*f[3] + P21*f[4] + P22*f[5];
    op[8] = P20*f[6] + P21*f[7] + P22*f[8];
}

extern "C" void kernel_launch(void* const* d_in, const int* in_sizes, int n_in,
                              void* d_out, int out_size, void* d_ws, size_t ws_size,
                              hipStream_t stream) {
    const float* F     = (const float*)d_in[0];
    const float* C     = (const float*)d_in[1];
    const float* w1    = (const float*)d_in[2];
    const float* b1    = (const float*)d_in[3];
    const float* w2    = (const float*)d_in[4];
    const float* b2    = (const float*)d_in[5];
    const float* w3    = (const float*)d_in[6];
    const float* b3    = (const float*)d_in[7];
    const float* w4    = (const float*)d_in[8];
    const float* b4    = (const float*)d_in[9];
    const float* w5    = (const float*)d_in[10];
    const float* b5    = (const float*)d_in[11];
    const float* trajw = (const float*)d_in[12];
    const int*   tids  = (const int*)d_in[13];
    float* out = (float*)d_out;
    unsigned short* wsu = (unsigned short*)d_ws;

    int B = in_sizes[0] / 9;

    prep_weights<<<16, 256, 0, stream>>>(w1, w2, w3, w4, wsu);

    int grid = (B + 127) / 128;
    stress_main<<<grid, 128, 0, stream>>>(F, C, b1, b2, b3, b4, w5, b5,
                                          trajw, tids, wsu, out, B);
}

// Round 7
// 350.787 us; speedup vs baseline: 5.8107x; 1.3394x over previous
//
#include <hip/hip_runtime.h>
#include <math.h>

typedef short short8 __attribute__((ext_vector_type(8)));
typedef float f32x4  __attribute__((ext_vector_type(4)));
typedef unsigned int uint2v __attribute__((ext_vector_type(2)));
typedef unsigned int uint4v __attribute__((ext_vector_type(4)));

__device__ __forceinline__ f32x4 mfma_bf16(short8 a, short8 b, f32x4 c) {
    return __builtin_amdgcn_mfma_f32_16x16x32_bf16(a, b, c, 0, 0, 0);
}

// ---- bf16 split helpers ----
// hi = truncate-to-bf16 (exact split: lo = x - hi, |lo| <= 2^-8|x|)
// lo stored RNE -> total err <= 2^-17|x|  (round-2-verified precision class)
__device__ __forceinline__ unsigned short f2bf_rne(float x) {
    union { float f; unsigned u; } v; v.f = x;
    unsigned r = v.u + 0x7fffu + ((v.u >> 16) & 1u);
    return (unsigned short)(r >> 16);
}
__device__ __forceinline__ float bf2f(unsigned short u) {
    union { unsigned u; float f; } v; v.u = ((unsigned)u) << 16;
    return v.f;
}
__device__ __forceinline__ float bf_hi(float x) {
    union { float f; unsigned u; } v; v.f = x; v.u &= 0xffff0000u; return v.f;
}
__device__ __forceinline__ unsigned rne_bits(float x) {
    union { float f; unsigned u; } v; v.f = x;
    return v.u + 0x7fffu + ((v.u >> 16) & 1u);
}
// pack bf16(x0) low16, bf16(x1) high16: 1 v_perm each
__device__ __forceinline__ unsigned pack_hi_trunc(float x0, float x1) {
    union { float f; unsigned u; } a, b; a.f = x0; b.f = x1;
    return __builtin_amdgcn_perm(b.u, a.u, 0x07060302u);
}
__device__ __forceinline__ unsigned pack_hi_rne(float x0, float x1) {
    return __builtin_amdgcn_perm(rne_bits(x1), rne_bits(x0), 0x07060302u);
}

// gelu exact-form via A&S 7.1.26 erf (|eps|<=1.5e-7); rcp/exp2 single-instr.
__device__ __forceinline__ float gelu(float x) {
    float z  = x * 0.70710678118654752f;
    float az = fabsf(z);
    float t  = __builtin_amdgcn_rcpf(fmaf(0.3275911f, az, 1.0f));
    float poly = fmaf(fmaf(fmaf(fmaf(1.061405429f, t, -1.453152027f), t,
                       1.421413741f), t, -0.284496736f), t, 0.254829592f);
    float e  = __builtin_amdgcn_exp2f(az * az * -1.4426950408889634f);
    float erfa = fmaf(-poly * t, e, 1.0f);
    float erfz = copysignf(erfa, z);
    return 0.5f * x * (1.0f + erfz);
}

// ---------- prep: weights -> A-frag bf16 hi/lo; biases -> C-frag f32 ----------
// u16 units: layer l in 0..3: base l*8192, blob ((mt*2+c)*2+p)*512 + lane*8,
//   value = W[k = c*32+(lane>>4)*8+j][n_out = mt*16+(lane&15)]  (A-operand frag)
// w5 at 32768: blob (c*2+p)*512 + lane*8; n_out = lane&15 (<9 else 0)
// biases (f32, base f32-idx 17408): ((l*4+mt)*64+lane)*4 + r = b[mt*16+(lane>>4)*4+r]
// b5 at f32-idx 17408+4096.
__global__ void prep_weights(const float* __restrict__ w1, const float* __restrict__ w2,
                             const float* __restrict__ w3, const float* __restrict__ w4,
                             const float* __restrict__ w5,
                             const float* __restrict__ b1, const float* __restrict__ b2,
                             const float* __restrict__ b3, const float* __restrict__ b4,
                             const float* __restrict__ b5,
                             unsigned short* __restrict__ wsu)
{
    int tid = blockIdx.x * blockDim.x + threadIdx.x;
    if (tid >= 5440) return;
    float* wsf = (float*)wsu;
    if (tid < 4096) {                     // layers 1..4 weight frags
        int l    = tid >> 10;
        int rem  = tid & 1023;
        int bi   = rem >> 6;              // 0..15
        int lane = rem & 63;
        int mt = bi >> 2;
        int c  = (bi >> 1) & 1;
        int p  = bi & 1;
        const float* W = (l == 0) ? w1 : (l == 1) ? w2 : (l == 2) ? w3 : w4;
        int K = (l == 0) ? 57 : 64;
        unsigned short* dst = wsu + l * 8192 + bi * 512 + lane * 8;
        int kb = c * 32 + (lane >> 4) * 8;
        int n  = mt * 16 + (lane & 15);
        #pragma unroll
        for (int j = 0; j < 8; ++j) {
            int k = kb + j;
            float v = (k < K) ? W[k * 64 + n] : 0.0f;
            unsigned short hi = f2bf_rne(v);
            dst[j] = (p == 0) ? hi : f2bf_rne(v - bf2f(hi));
        }
    } else if (tid < 4352) {              // w5 frags
        int rem  = tid - 4096;
        int bi   = rem >> 6;              // 0..3
        int lane = rem & 63;
        int c = bi >> 1;
        int p = bi & 1;
        unsigned short* dst = wsu + 32768 + bi * 512 + lane * 8;
        int kb = c * 32 + (lane >> 4) * 8;
        int n  = lane & 15;
        #pragma unroll
        for (int j = 0; j < 8; ++j) {
            int k = kb + j;
            float v = (n < 9) ? w5[k * 9 + n] : 0.0f;
            unsigned short hi = f2bf_rne(v);
            dst[j] = (p == 0) ? hi : f2bf_rne(v - bf2f(hi));
        }
    } else if (tid < 5376) {              // bias frags layers 1..4
        int rem  = tid - 4352;
        int l    = rem >> 8;
        int mt   = (rem >> 6) & 3;
        int lane = rem & 63;
        const float* bl = (l == 0) ? b1 : (l == 1) ? b2 : (l == 2) ? b3 : b4;
        float* dst = wsf + 17408 + ((l * 4 + mt) * 64 + lane) * 4;
        int q = lane >> 4;
        #pragma unroll
        for (int r = 0; r < 4; ++r) dst[r] = bl[mt * 16 + q * 4 + r];
    } else {                              // b5 frag
        int lane = tid - 5376;
        float* dst = wsf + 17408 + 4096 + lane * 4;
        int q = lane >> 4;
        #pragma unroll
        for (int r = 0; r < 4; ++r) {
            int row = q * 4 + r;
            dst[r] = (row < 9) ? b5[row] : 0.0f;
        }
    }
}

// ---------- main kernel ----------
// act layout: plane p (0=hi,1=lo) at p*9216 u16; elem ee (0..127, wave-private
// halves) row r (0..63, padded stride 72): act[p*9216 + ee*72 + r].
#define PL 9216

__global__ void __launch_bounds__(128) stress_main(
    const float* __restrict__ F, const float* __restrict__ Cin,
    const float* __restrict__ trajw, const int* __restrict__ traj_ids,
    const unsigned short* __restrict__ wfrag,
    float* __restrict__ out, int Btotal)
{
    __shared__ unsigned short act[2 * PL];        // 36,864 B
    const int t = threadIdx.x;
    const int b = blockIdx.x * 128 + t;
    const bool live = (b < Btotal);

    // ================= prologue: features + polar decomposition ============
    float f[9];
    float R00=0,R01=0,R02=0,R10=0,R11=0,R12=0,R20=0,R21=0,R22=0;
    float fv[64];
    #pragma unroll
    for (int i = 57; i < 64; ++i) fv[i] = 0.0f;

    if (live) {
        const float* Fp = F + b * 9;
        #pragma unroll
        for (int i = 0; i < 9; ++i) f[i] = Fp[i];
        const float* Cp = Cin + b * 9;
        #pragma unroll
        for (int i = 0; i < 9; ++i) fv[16 + i] = Cp[i];
        const int tid0 = traj_ids[0];
        const float* lp = trajw + tid0 * 32;
        #pragma unroll
        for (int e = 0; e < 32; ++e) fv[25 + e] = lp[e];

        float s00 = fmaf(f[0], f[0], fmaf(f[3], f[3], f[6] * f[6]));
        float s01 = fmaf(f[0], f[1], fmaf(f[3], f[4], f[6] * f[7]));
        float s02 = fmaf(f[0], f[2], fmaf(f[3], f[5], f[6] * f[8]));
        float s11 = fmaf(f[1], f[1], fmaf(f[4], f[4], f[7] * f[7]));
        float s12 = fmaf(f[1], f[2], fmaf(f[4], f[5], f[7] * f[8]));
        float s22 = fmaf(f[2], f[2], fmaf(f[5], f[5], f[8] * f[8]));
        fv[3] = s00; fv[4] = s01; fv[5] = s02;
        fv[6] = s01; fv[7] = s11; fv[8] = s12;
        fv[9] = s02; fv[10] = s12; fv[11] = s22;

        float det = f[0] * (f[4] * f[8] - f[5] * f[7])
                  - f[1] * (f[3] * f[8] - f[5] * f[6])
                  + f[2] * (f[3] * f[7] - f[4] * f[6]);
        float detc = det < 0.0f ? 1e-9f : det;
        fv[12] = detc;
        fv[13] = __builtin_amdgcn_logf(detc) * 0.6931471805599453f;
        float f00c = fmaxf(f[0], 1e-6f);
        fv[14] = f00c;
        fv[15] = __builtin_amdgcn_logf(f00c) * 0.6931471805599453f;

        // Jacobi eigendecomposition of FtF (round-1/2-verified algorithm)
        float a00 = s00, a01 = s01, a02 = s02, a11 = s11, a12 = s12, a22 = s22;
        float v00 = 1.f, v01 = 0.f, v02 = 0.f;
        float v10 = 0.f, v11 = 1.f, v12 = 0.f;
        float v20 = 0.f, v21 = 0.f, v22 = 1.f;
        auto rot = [](float& app, float& aqq, float& apq, float& arp, float& arq,
                      float& Vp0, float& Vq0, float& Vp1, float& Vq1, float& Vp2, float& Vq2) {
            float pq = apq;
            if (fabsf(pq) > 1e-20f) {
                float tau = (aqq - app) * 0.5f * __builtin_amdgcn_rcpf(pq);
                float tt = copysignf(__builtin_amdgcn_rcpf(
                               fabsf(tau) + __builtin_amdgcn_sqrtf(fmaf(tau, tau, 1.0f))), tau);
                float cc = __builtin_amdgcn_rsqf(fmaf(tt, tt, 1.0f));
                float ss = tt * cc;
                app = app - tt * pq;  aqq = aqq + tt * pq;  apq = 0.0f;
                float rp = arp, rq = arq;
                arp = cc * rp - ss * rq;  arq = ss * rp + cc * rq;
                float x0 = Vp0, y0 = Vq0; Vp0 = cc * x0 - ss * y0; Vq0 = ss * x0 + cc * y0;
                float x1 = Vp1, y1 = Vq1; Vp1 = cc * x1 - ss * y1; Vq1 = ss * x1 + cc * y1;
                float x2 = Vp2, y2 = Vq2; Vp2 = cc * x2 - ss * y2; Vq2 = ss * x2 + cc * y2;
            }
        };
        #pragma unroll
        for (int sweep = 0; sweep < 4; ++sweep) {
            rot(a00, a11, a01, a02, a12, v00, v01, v10, v11, v20, v21);
            rot(a00, a22, a02, a01, a12, v00, v02, v10, v12, v20, v22);
            rot(a11, a22, a12, a01, a02, v01, v02, v11, v12, v21, v22);
        }
        #define CSWAP(La, Lb, pA0, pB0, pA1, pB1, pA2, pB2)                     \
            if (La < Lb) { float t_;                                            \
                t_ = La; La = Lb; Lb = t_;   t_ = pA0; pA0 = pB0; pB0 = t_;     \
                t_ = pA1; pA1 = pB1; pB1 = t_; t_ = pA2; pA2 = pB2; pB2 = t_; }
        CSWAP(a00, a11, v00, v01, v10, v11, v20, v21)
        CSWAP(a00, a22, v00, v02, v10, v12, v20, v22)
        CSWAP(a11, a22, v01, v02, v11, v12, v21, v22)
        #undef CSWAP

        float sg0 = __builtin_amdgcn_sqrtf(fmaxf(a00, 0.0f));
        float sg1 = __builtin_amdgcn_sqrtf(fmaxf(a11, 0.0f));
        float sg2 = __builtin_amdgcn_sqrtf(fmaxf(a22, 0.0f));
        fv[0] = sg0; fv[1] = sg1; fv[2] = sg2;

        float i0 = __builtin_amdgcn_rcpf(fmaxf(sg0, 1e-12f));
        float i1 = __builtin_amdgcn_rcpf(fmaxf(sg1, 1e-12f));
        float i2 = __builtin_amdgcn_rcpf(fmaxf(sg2, 1e-12f));
        float A00 = i0*v00*v00 + i1*v01*v01 + i2*v02*v02;
        float A01 = i0*v00*v10 + i1*v01*v11 + i2*v02*v12;
        float A02 = i0*v00*v20 + i1*v01*v21 + i2*v02*v22;
        float A11 = i0*v10*v10 + i1*v11*v11 + i2*v12*v12;
        float A12 = i0*v10*v20 + i1*v11*v21 + i2*v12*v22;
        float A22 = i0*v20*v20 + i1*v21*v21 + i2*v22*v22;
        R00 = f[0]*A00 + f[1]*A01 + f[2]*A02;
        R01 = f[0]*A01 + f[1]*A11 + f[2]*A12;
        R02 = f[0]*A02 + f[1]*A12 + f[2]*A22;
        R10 = f[3]*A00 + f[4]*A01 + f[5]*A02;
        R11 = f[3]*A01 + f[4]*A11 + f[5]*A12;
        R12 = f[3]*A02 + f[4]*A12 + f[5]*A22;
        R20 = f[6]*A00 + f[7]*A01 + f[8]*A02;
        R21 = f[6]*A01 + f[7]*A11 + f[8]*A12;
        R22 = f[6]*A02 + f[7]*A12 + f[8]*A22;
    } else {
        #pragma unroll
        for (int i = 0; i < 57; ++i) fv[i] = 0.0f;
        #pragma unroll
        for (int i = 0; i < 9; ++i) f[i] = 0.0f;
    }

    // write feature column (rows 0..63) hi/lo, 8+8 x ds_write_b128
    {
        const int base = t * 72;
        #pragma unroll
        for (int ch = 0; ch < 8; ++ch) {
            uint4v vh, vl;
            #pragma unroll
            for (int pr = 0; pr < 4; ++pr) {
                float x0 = fv[ch * 8 + pr * 2], x1 = fv[ch * 8 + pr * 2 + 1];
                float h0 = bf_hi(x0), h1 = bf_hi(x1);
                vh[pr] = pack_hi_trunc(x0, x1);
                vl[pr] = pack_hi_rne(x0 - h0, x1 - h1);
            }
            *(uint4v*)&act[base + ch * 8]      = vh;
            *(uint4v*)&act[PL + base + ch * 8] = vl;
        }
    }

    // ================= MLP: 4 x (64->64, gelu), A=weights, B=activations ====
    // Wave-private elems (wave wv owns ee in [wv*64, wv*64+64)) -> no barriers.
    const int wv   = t >> 6;
    const int lane = t & 63;
    const int q    = lane >> 4;
    const int e    = lane & 15;
    const int wbase = wv * 64;
    const float* bias_f = (const float*)wfrag + 17408;

    for (int l = 0; l < 4; ++l) {
        const unsigned short* wb = wfrag + l * 8192;
        short8 Ah[4][2], Al[4][2];
        f32x4 bfr[4];
        #pragma unroll
        for (int mt = 0; mt < 4; ++mt) {
            #pragma unroll
            for (int c = 0; c < 2; ++c) {
                Ah[mt][c] = *(const short8*)(wb + ((mt * 2 + c) * 2 + 0) * 512 + lane * 8);
                Al[mt][c] = *(const short8*)(wb + ((mt * 2 + c) * 2 + 1) * 512 + lane * 8);
            }
            bfr[mt] = *(const f32x4*)(bias_f + ((l * 4 + mt) * 64 + lane) * 4);
        }
        #pragma unroll
        for (int et = 0; et < 4; ++et) {
            const int ebase = (wbase + et * 16 + e) * 72;
            short8 Bh0 = *(const short8*)&act[ebase + q * 8];
            short8 Bh1 = *(const short8*)&act[ebase + 32 + q * 8];
            short8 Bl0 = *(const short8*)&act[PL + ebase + q * 8];
            short8 Bl1 = *(const short8*)&act[PL + ebase + 32 + q * 8];
            #pragma unroll
            for (int mt = 0; mt < 4; ++mt) {
                f32x4 acc = bfr[mt];
                acc = mfma_bf16(Ah[mt][0], Bh0, acc);
                acc = mfma_bf16(Ah[mt][1], Bh1, acc);
                acc = mfma_bf16(Al[mt][0], Bh0, acc);
                acc = mfma_bf16(Al[mt][1], Bh1, acc);
                acc = mfma_bf16(Ah[mt][0], Bl0, acc);
                acc = mfma_bf16(Ah[mt][1], Bl1, acc);
                float g0 = gelu(acc[0]), g1 = gelu(acc[1]);
                float g2 = gelu(acc[2]), g3 = gelu(acc[3]);
                float h0 = bf_hi(g0), h1 = bf_hi(g1), h2 = bf_hi(g2), h3 = bf_hi(g3);
                uint2v wh = { pack_hi_trunc(g0, g1), pack_hi_trunc(g2, g3) };
                uint2v wl = { pack_hi_rne(g0 - h0, g1 - h1), pack_hi_rne(g2 - h2, g3 - h3) };
                const int ro = ebase + mt * 16 + q * 4;
                *(uint2v*)&act[ro]      = wh;
                *(uint2v*)&act[PL + ro] = wl;
            }
        }
    }

    // ================= layer 5: 64 -> 9(pad16) via MFMA =====================
    // fp32 staging aliased into this wave's own plane-0 region; per-et
    // read-before-write order safe (writes of iter et stay below reads of et'>et).
    float* obf = (float*)(act + wv * 4608);     // 64 elems x 12 f32 = 3072 B
    {
        const unsigned short* wb5 = wfrag + 32768;
        short8 A5h[2], A5l[2];
        #pragma unroll
        for (int c = 0; c < 2; ++c) {
            A5h[c] = *(const short8*)(wb5 + (c * 2 + 0) * 512 + lane * 8);
            A5l[c] = *(const short8*)(wb5 + (c * 2 + 1) * 512 + lane * 8);
        }
        f32x4 b5f = *(const f32x4*)(bias_f + 4096 + lane * 4);
        #pragma unroll
        for (int et = 0; et < 4; ++et) {
            const int ebase = (wbase + et * 16 + e) * 72;
            short8 Bh0 = *(const short8*)&act[ebase + q * 8];
            short8 Bh1 = *(const short8*)&act[ebase + 32 + q * 8];
            short8 Bl0 = *(const short8*)&act[PL + ebase + q * 8];
            short8 Bl1 = *(const short8*)&act[PL + ebase + 32 + q * 8];
            f32x4 acc = b5f;
            acc = mfma_bf16(A5h[0], Bh0, acc);
            acc = mfma_bf16(A5h[1], Bh1, acc);
            acc = mfma_bf16(A5l[0], Bh0, acc);
            acc = mfma_bf16(A5l[1], Bh1, acc);
            acc = mfma_bf16(A5h[0], Bl0, acc);
            acc = mfma_bf16(A5h[1], Bl1, acc);
            if (q < 3) {
                const int le = et * 16 + e;
                *(f32x4*)&obf[le * 12 + q * 4] = acc;
            }
        }
    }

    // ================= epilogue: symmetrize, P = R*xs, cauchy = P*F^T =======
    if (!live) return;

    float o[9];
    {
        const float* orow = obf + lane * 12;
        #pragma unroll
        for (int j = 0; j < 9; ++j) o[j] = orow[j];
    }

    float xs00 = o[0];
    float xs01 = 0.5f * (o[1] + o[3]);
    float xs02 = 0.5f * (o[2] + o[6]);
    float xs11 = o[4];
    float xs12 = 0.5f * (o[5] + o[7]);
    float xs22 = o[8];

    float P00 = R00*xs00 + R01*xs01 + R02*xs02;
    float P01 = R00*xs01 + R01*xs11 + R02*xs12;
    float P02 = R00*xs02 + R01*xs12 + R02*xs22;
    float P10 = R10*xs00 + R11*xs01 + R12*xs02;
    float P11 = R10*xs01 + R11*xs11 + R12*xs12;
    float P12 = R10*xs02 + R11*xs12 + R12*xs22;
    float P20 = R20*xs00 + R21*xs01 + R22*xs02;
    float P21 = R20*xs01 + R21*xs11 + R22*xs12;
    float P22 = R20*xs02 + R21*xs12 + R22*xs22;

    // cauchy[i][j] = sum_k P[i][k] * F[j][k]
    // NOTE: op[7] = P20*f[3] + P21*f[4] + P22*f[5] — the f[5] term was
    // mis-typed as f[7] in rounds 3-6; that single index caused all four
    // identical 7.23e-3 failures.
    float* op = out + b * 9;
    op[0] = P00*f[0] + P01*f[1] + P02*f[2];
    op[1] = P00*f[3] + P01*f[4] + P02*f[5];
    op[2] = P00*f[6] + P01*f[7] + P02*f[8];
    op[3] = P10*f[0] + P11*f[1] + P12*f[2];
    op[4] = P10*f[3] + P11*f[4] + P12*f[5];
    op[5] = P10*f[6] + P11*f[7] + P12*f[8];
    op[6] = P20*f[0] + P21*f[1] + P22*f[2];
    op[7] = P20*f[3] + P21*f[4] + P22*f[5];
    op[8] = P20*f[6] + P21*f[7] + P22*f[8];
}

extern "C" void kernel_launch(void* const* d_in, const int* in_sizes, int n_in,
                              void* d_out, int out_size, void* d_ws, size_t ws_size,
                              hipStream_t stream) {
    const float* F     = (const float*)d_in[0];
    const float* C     = (const float*)d_in[1];
    const float* w1    = (const float*)d_in[2];
    const float* b1    = (const float*)d_in[3];
    const float* w2    = (const float*)d_in[4];
    const float* b2    = (const float*)d_in[5];
    const float* w3    = (const float*)d_in[6];
    const float* b3    = (const float*)d_in[7];
    const float* w4    = (const float*)d_in[8];
    const float* b4    = (const float*)d_in[9];
    const float* w5    = (const float*)d_in[10];
    const float* b5    = (const float*)d_in[11];
    const float* trajw = (const float*)d_in[12];
    const int*   tids  = (const int*)d_in[13];
    float* out = (float*)d_out;
    unsigned short* wsu = (unsigned short*)d_ws;

    int B = in_sizes[0] / 9;

    prep_weights<<<22, 256, 0, stream>>>(w1, w2, w3, w4, w5,
                                         b1, b2, b3, b4, b5, wsu);

    int grid = (B + 127) / 128;
    stress_main<<<grid, 128, 0, stream>>>(F, C, trajw, tids, wsu, out, B);
}